// Round 9
// baseline (587.726 us; speedup 1.0000x reference)
//
#include <hip/hip_runtime.h>

namespace {
constexpr int T_STEPS = 50;
constexpr int BATCH_N = 131072;
constexpr int HIDDEN  = 100;
}

// Pre-kernel: interleave weights into d_ws as [h][4] = {w1a, w1b, w20, w21}.
__global__ void interleave_weights(const float* __restrict__ W1,
                                   const float* __restrict__ W2,
                                   float* __restrict__ wi) {
    int h = blockIdx.x * 64 + threadIdx.x;
    if (h < HIDDEN) {
        wi[4 * h + 0] = W1[2 * h];
        wi[4 * h + 1] = W1[2 * h + 1];
        wi[4 * h + 2] = W2[h];
        wi[4 * h + 3] = W2[HIDDEN + h];
    }
}

#define REP100(X) \
  X(0) X(1) X(2) X(3) X(4) X(5) X(6) X(7) X(8) X(9) \
  X(10) X(11) X(12) X(13) X(14) X(15) X(16) X(17) X(18) X(19) \
  X(20) X(21) X(22) X(23) X(24) X(25) X(26) X(27) X(28) X(29) \
  X(30) X(31) X(32) X(33) X(34) X(35) X(36) X(37) X(38) X(39) \
  X(40) X(41) X(42) X(43) X(44) X(45) X(46) X(47) X(48) X(49) \
  X(50) X(51) X(52) X(53) X(54) X(55) X(56) X(57) X(58) X(59) \
  X(60) X(61) X(62) X(63) X(64) X(65) X(66) X(67) X(68) X(69) \
  X(70) X(71) X(72) X(73) X(74) X(75) X(76) X(77) X(78) X(79) \
  X(80) X(81) X(82) X(83) X(84) X(85) X(86) X(87) X(88) X(89) \
  X(90) X(91) X(92) X(93) X(94) X(95) X(96) X(97) X(98) X(99)

// Named scalars -> guaranteed register residency (no array to demote).
#define SNN_DECL(H) float mm##H = 0.0f, ss##H = 0.0f;

// Bitwise-identical arithmetic to the R7/R8 PASS:
//   cur = fmaf(x1, w1b, x0*w1a)
//   m   = fmaf(s_prev, -0.5f, fmaf(0.9f, m, cur))
//   s   = (m > 0.5f) ? 1.0f : 0.0f   (carried in ss##H, not recomputed)
//   acc = ascending-h serial fmaf chain (exact products)
#define SNN_STEP(H) { \
    const float w1a = wi[4 * H + 0]; \
    const float w1b = wi[4 * H + 1]; \
    const float w20 = wi[4 * H + 2]; \
    const float w21 = wi[4 * H + 3]; \
    const float cur = fmaf(x1, w1b, x0 * w1a); \
    mm##H = fmaf(ss##H, -0.5f, fmaf(0.9f, mm##H, cur)); \
    ss##H = (mm##H > 0.5f) ? 1.0f : 0.0f; \
    acc0 = fmaf(ss##H, w20, acc0); \
    acc1 = fmaf(ss##H, w21, acc1); }

__global__ __launch_bounds__(256, 2)
void snn_touter_reg(const unsigned int* __restrict__ x_u,
                    const float* __restrict__ wi,
                    unsigned int* __restrict__ out_u)
{
#pragma clang fp contract(off)
    const int b = blockIdx.x * 256 + threadIdx.x;

    REP100(SNN_DECL)

    float m20 = 0.0f, m21 = 0.0f, s20 = 0.0f, s21 = 0.0f;  // layer-2 state
    const size_t mem_off = (size_t)T_STEPS * BATCH_N * 2;

    for (int t = 0; t < T_STEPS; ++t) {
        const size_t cell = ((size_t)t * BATCH_N + b) * 2;
        const float x0 = __uint_as_float(x_u[cell]);
        const float x1 = __uint_as_float(x_u[cell + 1]);

        float acc0 = 0.0f, acc1 = 0.0f;
        REP100(SNN_STEP)

        m20 = fmaf(s20, -0.5f, fmaf(0.9f, m20, acc0));
        m21 = fmaf(s21, -0.5f, fmaf(0.9f, m21, acc1));
        s20 = (m20 > 0.5f) ? 1.0f : 0.0f;
        s21 = (m21 > 0.5f) ? 1.0f : 0.0f;

        out_u[cell]               = __float_as_uint(s20);
        out_u[cell + 1]           = __float_as_uint(s21);
        out_u[mem_off + cell]     = __float_as_uint(m20);
        out_u[mem_off + cell + 1] = __float_as_uint(m21);
    }
}

extern "C" void kernel_launch(void* const* d_in, const int* in_sizes, int n_in,
                              void* d_out, int out_size, void* d_ws, size_t ws_size,
                              hipStream_t stream) {
    // Robust input mapping: x = the unique large buffer; W1 precedes W2 among
    // the rest (holds under both dict order [x,W1,W2] and sorted [W1,W2,x]).
    int big = 0;
    for (int i = 1; i < n_in; ++i) if (in_sizes[i] > in_sizes[big]) big = i;
    const void* ptrs[3] = {nullptr, nullptr, nullptr};  // x, W1, W2
    int k = 1;
    ptrs[0] = d_in[big];
    for (int i = 0; i < n_in; ++i) {
        if (i == big) continue;
        ptrs[k++] = d_in[i];
    }
    const unsigned int* x_u = (const unsigned int*)ptrs[0];
    const float* W1 = (const float*)ptrs[1];
    const float* W2 = (const float*)ptrs[2];
    float* wi = (float*)d_ws;                 // 400 floats scratch
    unsigned int* out_u = (unsigned int*)d_out;

    hipLaunchKernelGGL(interleave_weights, dim3(2), dim3(64), 0, stream,
                       W1, W2, wi);
    hipLaunchKernelGGL(snn_touter_reg, dim3(BATCH_N / 256), dim3(256), 0,
                       stream, x_u, wi, out_u);
}

// Round 10
// 228.252 us; speedup vs baseline: 2.5749x; 2.5749x over previous
//
#include <hip/hip_runtime.h>

namespace {
constexpr int T_STEPS = 50;
constexpr int BATCH_N = 131072;
constexpr int HIDDEN  = 100;
}

// Pre-kernel: interleave weights into d_ws as [h][4] = {w1a, w1b, w20, w21}
// -> 16B-aligned uniform reads in the main kernel (s_load_dwordx4, scalar
// cache, zero VALU/LDS cost).
__global__ void interleave_weights(const float* __restrict__ W1,
                                   const float* __restrict__ W2,
                                   float* __restrict__ wi) {
    int h = blockIdx.x * 64 + threadIdx.x;
    if (h < HIDDEN) {
        wi[4 * h + 0] = W1[2 * h];
        wi[4 * h + 1] = W1[2 * h + 1];
        wi[4 * h + 2] = W2[h];
        wi[4 * h + 3] = W2[HIDDEN + h];
    }
}

#define REP100(X) \
  X(0) X(1) X(2) X(3) X(4) X(5) X(6) X(7) X(8) X(9) \
  X(10) X(11) X(12) X(13) X(14) X(15) X(16) X(17) X(18) X(19) \
  X(20) X(21) X(22) X(23) X(24) X(25) X(26) X(27) X(28) X(29) \
  X(30) X(31) X(32) X(33) X(34) X(35) X(36) X(37) X(38) X(39) \
  X(40) X(41) X(42) X(43) X(44) X(45) X(46) X(47) X(48) X(49) \
  X(50) X(51) X(52) X(53) X(54) X(55) X(56) X(57) X(58) X(59) \
  X(60) X(61) X(62) X(63) X(64) X(65) X(66) X(67) X(68) X(69) \
  X(70) X(71) X(72) X(73) X(74) X(75) X(76) X(77) X(78) X(79) \
  X(80) X(81) X(82) X(83) X(84) X(85) X(86) X(87) X(88) X(89) \
  X(90) X(91) X(92) X(93) X(94) X(95) X(96) X(97) X(98) X(99)

#define SNN_DECL(H) float mm##H = 0.0f;

// Bitwise-identical arithmetic to the R7 PASS:
//   cur = fmaf(x1, w1b, x0*w1a)
//   sp  = (m_old > 0.5f) ? 1 : 0            (recomputed from m, not carried)
//   m   = fmaf(sp, -0.5f, fmaf(0.9f, m_old, cur))
//   sc  = (m > 0.5f) ? 1 : 0
//   acc = ascending-h serial fmaf chain (exact products)
#define SNN_STEP(H) { \
    const float4 w = wp[H];                       /* uniform -> s_load x4 */ \
    const float cur = fmaf(x1, w.y, x0 * w.x); \
    const float sp  = (mm##H > 0.5f) ? 1.0f : 0.0f; \
    mm##H = fmaf(sp, -0.5f, fmaf(0.9f, mm##H, cur)); \
    const float sc  = (mm##H > 0.5f) ? 1.0f : 0.0f; \
    acc0 = fmaf(sc, w.z, acc0); \
    acc1 = fmaf(sc, w.w, acc1); }

__global__
__attribute__((amdgpu_flat_work_group_size(256, 256), amdgpu_waves_per_eu(2, 2)))
void snn_touter_reg(const unsigned int* __restrict__ x_u,
                    const float* __restrict__ wi,
                    unsigned int* __restrict__ out_u)
{
#pragma clang fp contract(off)
    const int b = blockIdx.x * 256 + threadIdx.x;
    const float4* wp = reinterpret_cast<const float4*>(wi);

    REP100(SNN_DECL)

    float m20 = 0.0f, m21 = 0.0f, s20 = 0.0f, s21 = 0.0f;  // layer-2 state
    const size_t mem_off = (size_t)T_STEPS * BATCH_N * 2;

    for (int t = 0; t < T_STEPS; ++t) {
        const size_t cell = ((size_t)t * BATCH_N + b) * 2;
        const float x0 = __uint_as_float(x_u[cell]);
        const float x1 = __uint_as_float(x_u[cell + 1]);

        float acc0 = 0.0f, acc1 = 0.0f;
        REP100(SNN_STEP)

        m20 = fmaf(s20, -0.5f, fmaf(0.9f, m20, acc0));
        m21 = fmaf(s21, -0.5f, fmaf(0.9f, m21, acc1));
        s20 = (m20 > 0.5f) ? 1.0f : 0.0f;
        s21 = (m21 > 0.5f) ? 1.0f : 0.0f;

        out_u[cell]               = __float_as_uint(s20);
        out_u[cell + 1]           = __float_as_uint(s21);
        out_u[mem_off + cell]     = __float_as_uint(m20);
        out_u[mem_off + cell + 1] = __float_as_uint(m21);
    }
}

extern "C" void kernel_launch(void* const* d_in, const int* in_sizes, int n_in,
                              void* d_out, int out_size, void* d_ws, size_t ws_size,
                              hipStream_t stream) {
    // Robust input mapping: x = the unique large buffer; W1 precedes W2 among
    // the rest (holds under both dict order [x,W1,W2] and sorted [W1,W2,x]).
    int big = 0;
    for (int i = 1; i < n_in; ++i) if (in_sizes[i] > in_sizes[big]) big = i;
    const void* ptrs[3] = {nullptr, nullptr, nullptr};  // x, W1, W2
    int k = 1;
    ptrs[0] = d_in[big];
    for (int i = 0; i < n_in; ++i) {
        if (i == big) continue;
        ptrs[k++] = d_in[i];
    }
    const unsigned int* x_u = (const unsigned int*)ptrs[0];
    const float* W1 = (const float*)ptrs[1];
    const float* W2 = (const float*)ptrs[2];
    float* wi = (float*)d_ws;                 // 400 floats scratch (16B aligned)
    unsigned int* out_u = (unsigned int*)d_out;

    hipLaunchKernelGGL(interleave_weights, dim3(2), dim3(64), 0, stream,
                       W1, W2, wi);
    hipLaunchKernelGGL(snn_touter_reg, dim3(BATCH_N / 256), dim3(256), 0,
                       stream, x_u, wi, out_u);
}